// Round 3
// baseline (213.037 us; speedup 1.0000x reference)
//
#include <hip/hip_runtime.h>
#include <hip/hip_bf16.h>

// OuterMean: algebraic collapse.
// out[i,j,d] = L[i,d] + R[j,d], where
//   S[i,d] = mean_m LN(x)[m,i,d]                    (LN over last dim, eps 1e-5)
//   L = (S @ w_left  + b_left ) @ w_out
//   R = (S @ w_right + b_right) @ w_out + b_out     (b_out folded into R)
//
// Workspace (floats): L[0:65536], R[65536:131072]

#define DIM 128
#define NI  512
#define NM  256

typedef float vfloat4 __attribute__((ext_vector_type(4)));

// ---------- Kernel A: fused LayerNorm + mean_m + both projection chains -----
// grid = 512 (one block per i), block = 512 threads (8 waves).
// Phase 1: each 32-lane half-wave owns one LN row per iteration (float4/lane,
//          5-stage 32-lane butterfly). 16 half-waves x 16 iters = 256 m rows.
// Phase 2: tree-reduce the 16 partial sums -> S[i,:] in LDS (no global S).
// Phase 3: threads 0..255 compute L[i,:] / R[i,:] via the two tiny GEMM chains.
__global__ __launch_bounds__(512) void ln_proj_kernel(
    const float* __restrict__ x,
    const float* __restrict__ ln_g,
    const float* __restrict__ ln_b,
    const float* __restrict__ w_left,  const float* __restrict__ b_left,
    const float* __restrict__ w_right, const float* __restrict__ b_right,
    const float* __restrict__ w_out,   const float* __restrict__ b_out,
    float* __restrict__ L, float* __restrict__ R)
{
    const int i      = blockIdx.x;     // 0..511
    const int tid    = threadIdx.x;    // 0..511
    const int lane32 = tid & 31;       // float4 slot within the 128-d row
    const int grp    = tid >> 5;       // 0..15: which m-stream this half-wave owns

    const vfloat4 g4 = *(const vfloat4*)(ln_g + 4 * lane32);
    const vfloat4 e4 = *(const vfloat4*)(ln_b + 4 * lane32);

    float a0 = 0.f, a1 = 0.f, a2 = 0.f, a3 = 0.f;
    const vfloat4* __restrict__ x4 = (const vfloat4*)x;

    #pragma unroll 4
    for (int t = 0; t < NM / 16; ++t) {
        const int m = grp + (t << 4);
        const vfloat4 v = x4[((size_t)(m * NI + i) << 5) + lane32];

        float s  = v.x + v.y + v.z + v.w;
        float s2 = v.x*v.x + v.y*v.y + v.z*v.z + v.w*v.w;
        // butterfly within the 32-lane half (xor offsets < 32 never cross halves)
        #pragma unroll
        for (int off = 16; off; off >>= 1) {
            s  += __shfl_xor(s,  off);
            s2 += __shfl_xor(s2, off);
        }
        const float mu   = s * (1.f/128.f);
        const float rstd = rsqrtf(s2 * (1.f/128.f) - mu*mu + 1e-5f);

        a0 += (v.x - mu) * rstd * g4.x + e4.x;
        a1 += (v.y - mu) * rstd * g4.y + e4.y;
        a2 += (v.z - mu) * rstd * g4.z + e4.z;
        a3 += (v.w - mu) * rstd * g4.w + e4.w;
    }

    __shared__ vfloat4 sacc[512];
    __shared__ float   sS[DIM];
    __shared__ float   sT[2 * DIM];    // [0:128) left hidden, [128:256) right

    vfloat4 mine;
    mine.x = a0; mine.y = a1; mine.z = a2; mine.w = a3;
    sacc[tid] = mine;
    __syncthreads();

    if (tid < 32) {
        vfloat4 t = sacc[tid];
        #pragma unroll
        for (int gg = 1; gg < 16; ++gg)
            t += sacc[(gg << 5) + tid];
        const float inv = 1.f / (float)NM;
        sS[4*tid + 0] = t.x * inv;
        sS[4*tid + 1] = t.y * inv;
        sS[4*tid + 2] = t.z * inv;
        sS[4*tid + 3] = t.w * inv;
    }
    __syncthreads();

    // Stage 1: T = S[i,:] @ W + bias   (W row-major (DIM,HID): coalesced on h)
    if (tid < 256) {
        const int  h   = tid & 127;
        const bool isR = (tid >= 128);
        const float* __restrict__ W = isR ? w_right : w_left;
        float acc = isR ? b_right[h] : b_left[h];
        #pragma unroll 8
        for (int d = 0; d < DIM; ++d)
            acc += sS[d] * W[(d << 7) + h];
        sT[tid] = acc;
    }
    __syncthreads();

    // Stage 2: row @ w_out  (+ b_out on the right path only)
    if (tid < 256) {
        const int  h   = tid & 127;
        const bool isR = (tid >= 128);
        const float* __restrict__ T = isR ? (sT + DIM) : sT;
        float acc = isR ? b_out[h] : 0.f;
        #pragma unroll 8
        for (int hh = 0; hh < DIM; ++hh)
            acc += T[hh] * w_out[(hh << 7) + h];
        (isR ? R : L)[((size_t)i << 7) + h] = acc;
    }
}

// ---------- Kernel B: out[i,j,d] = L[i,d] + R[j,d] --------------------------
// grid = 512 (one block per i), block = 512. L[i,:] register-resident (one
// load per thread); R (256 KB) stays L2-hot; output streamed with
// nontemporal 16B stores (134 MB, don't pollute L2).
__global__ __launch_bounds__(512) void expand_kernel(
    const vfloat4* __restrict__ L4,
    const vfloat4* __restrict__ R4,
    vfloat4* __restrict__ out4)
{
    const int i  = blockIdx.x;
    const int d4 = threadIdx.x & 31;   // float4 slot in d-row
    const int jg = threadIdx.x >> 5;   // 0..15

    const vfloat4 l = L4[(i << 5) + d4];
    vfloat4* __restrict__ outb = out4 + ((size_t)i << 14);   // i * 512 * 32

    #pragma unroll 4
    for (int it = 0; it < 32; ++it) {
        const int j = jg + (it << 4);
        const vfloat4 r = R4[(j << 5) + d4];
        const vfloat4 o = l + r;
        __builtin_nontemporal_store(o, &outb[(j << 5) + d4]);
    }
}

extern "C" void kernel_launch(void* const* d_in, const int* in_sizes, int n_in,
                              void* d_out, int out_size, void* d_ws, size_t ws_size,
                              hipStream_t stream) {
    const float* x       = (const float*)d_in[0];
    const float* ln_g    = (const float*)d_in[1];
    const float* ln_b    = (const float*)d_in[2];
    const float* w_left  = (const float*)d_in[3];
    const float* b_left  = (const float*)d_in[4];
    const float* w_right = (const float*)d_in[5];
    const float* b_right = (const float*)d_in[6];
    const float* w_out   = (const float*)d_in[7];
    const float* b_out   = (const float*)d_in[8];

    float* L = (float*)d_ws;            // 512*128
    float* R = L + NI * DIM;            // 512*128

    ln_proj_kernel<<<NI, 512, 0, stream>>>(x, ln_g, ln_b,
                                           w_left, b_left, w_right, b_right,
                                           w_out, b_out, L, R);
    expand_kernel<<<NI, 512, 0, stream>>>((const vfloat4*)L,
                                          (const vfloat4*)R,
                                          (vfloat4*)d_out);
}